// Round 1
// baseline (247.876 us; speedup 1.0000x reference)
//
#include <hip/hip_runtime.h>

#define NB   16
#define NSQ  1024
#define NSKV 1024
#define ND   256

typedef __bf16 bf16x8 __attribute__((ext_vector_type(8)));
typedef float  f32x4  __attribute__((ext_vector_type(4)));

// Phase structure:
//  phase 1: S = Q K^T via mfma_f32_16x16x32_bf16; e = mask ? exp(exp(S)/16) : 0
//           written unnormalized to p region; Z per row accumulated in-wave.
//  phase 2: re-read own e tile, scale by 1/Z, write p, accumulate colsum.
// Block: 4 waves, 64 q-rows (wave w owns rows w*16..w*16+15, all 1024 k).
__global__ __launch_bounds__(256) void attn_e_kernel(
    const float* __restrict__ Q, const float* __restrict__ K,
    const int* __restrict__ mask, float* __restrict__ out_p,
    float* __restrict__ colsum)
{
    const int b    = blockIdx.x >> 4;    // 16 q-tiles per batch
    const int qt   = blockIdx.x & 15;
    const int q0   = qt * 64;
    const int tid  = threadIdx.x;
    const int lane = tid & 63;
    const int w    = tid >> 6;
    const int m    = lane & 15;          // MFMA row (A) / col (B) / C col
    const int kg   = lane >> 4;          // quad: k-slice for A/B, row-group for C

    __shared__ __bf16 Ks[64 * 264];      // 64 K-rows, stride 264 (2-way bank = free)
    __shared__ float  Zs[64];

    // ---- A fragments: Q rows for this wave, converted f32->bf16, kept in regs ----
    bf16x8 afrag[8];
    {
        const float* qbase = Q + ((size_t)(b * NSQ + q0 + w * 16 + m)) * ND;
        #pragma unroll
        for (int dc = 0; dc < 8; ++dc) {
            const float* p4 = qbase + dc * 32 + kg * 8;
            float4 x = *(const float4*)(p4);
            float4 y = *(const float4*)(p4 + 4);
            bf16x8 a;
            a[0] = (__bf16)x.x; a[1] = (__bf16)x.y; a[2] = (__bf16)x.z; a[3] = (__bf16)x.w;
            a[4] = (__bf16)y.x; a[5] = (__bf16)y.y; a[6] = (__bf16)y.z; a[7] = (__bf16)y.w;
            afrag[dc] = a;
        }
    }

    float zacc[4] = {0.f, 0.f, 0.f, 0.f};
    const size_t bq0 = (size_t)b * NSQ + q0;   // global row base of this block

    for (int kc = 0; kc < NSKV; kc += 64) {
        __syncthreads();
        // ---- stage K rows [kc, kc+64) into LDS as bf16 ----
        {
            const float4* kb = (const float4*)(K + ((size_t)(b * NSKV + kc)) * ND);
            #pragma unroll
            for (int i = 0; i < 16; ++i) {
                int f  = tid + (i << 8);
                int r  = f >> 6;
                int c4 = f & 63;
                float4 v = kb[r * 64 + c4];
                __bf16* dst = &Ks[r * 264 + c4 * 4];
                dst[0] = (__bf16)v.x; dst[1] = (__bf16)v.y;
                dst[2] = (__bf16)v.z; dst[3] = (__bf16)v.w;
            }
        }
        __syncthreads();

        #pragma unroll
        for (int nt = 0; nt < 4; ++nt) {
            const int kcol = kc + nt * 16 + m;
            const size_t base0 = (bq0 + w * 16 + kg * 4) * (size_t)NSKV + kcol;

            // prefetch the 4 mask words this lane needs (compiler hoists)
            int msk[4];
            #pragma unroll
            for (int i = 0; i < 4; ++i) msk[i] = mask[base0 + (size_t)i * NSKV];

            f32x4 acc = {0.f, 0.f, 0.f, 0.f};
            #pragma unroll
            for (int dc = 0; dc < 8; ++dc) {
                bf16x8 bfr = *(const bf16x8*)&Ks[(nt * 16 + m) * 264 + dc * 32 + kg * 8];
                acc = __builtin_amdgcn_mfma_f32_16x16x32_bf16(afrag[dc], bfr, acc, 0, 0, 0);
            }

            #pragma unroll
            for (int i = 0; i < 4; ++i) {
                float e = msk[i] ? __expf(__expf(acc[i]) * 0.0625f) : 0.f;
                out_p[base0 + (size_t)i * NSKV] = e;
                zacc[i] += e;
            }
        }
    }

    // ---- reduce Z across the 16 lanes (c = lane&15) of each quad ----
    #pragma unroll
    for (int i = 0; i < 4; ++i) {
        float z = zacc[i];
        z += __shfl_xor(z, 1);
        z += __shfl_xor(z, 2);
        z += __shfl_xor(z, 4);
        z += __shfl_xor(z, 8);
        if (m == 0) Zs[w * 16 + kg * 4 + i] = z;
    }
    __syncthreads();

    // ---- phase 2: normalize own tile, accumulate column sums ----
    float csum[4] = {0.f, 0.f, 0.f, 0.f};
    for (int r = 0; r < 64; ++r) {
        const float invZ = 1.0f / Zs[r];
        const size_t base = (bq0 + r) * (size_t)NSKV;
        #pragma unroll
        for (int j = 0; j < 4; ++j) {
            const int k = (j << 8) + tid;
            float p = out_p[base + k] * invZ;
            out_p[base + k] = p;
            csum[j] += p;
        }
    }
    #pragma unroll
    for (int j = 0; j < 4; ++j)
        atomicAdd(&colsum[b * NSKV + (j << 8) + tid], csum[j]);
}

// out[b,d] = sum_k colsum[b,k] * V[b,k,d]; grid = NB*16 blocks, k split 16 ways
__global__ __launch_bounds__(256) void attn_out_kernel(
    const float* __restrict__ colsum, const float* __restrict__ V,
    float* __restrict__ out)
{
    const int b  = blockIdx.x >> 4;
    const int ks = (blockIdx.x & 15) << 6;   // 64 k per block
    const int d  = threadIdx.x;
    float acc = 0.f;
    #pragma unroll 8
    for (int k = ks; k < ks + 64; ++k) {
        acc += colsum[b * NSKV + k] * V[((size_t)(b * NSKV + k)) * ND + d];
    }
    atomicAdd(&out[b * ND + d], acc);
}

extern "C" void kernel_launch(void* const* d_in, const int* in_sizes, int n_in,
                              void* d_out, int out_size, void* d_ws, size_t ws_size,
                              hipStream_t stream)
{
    (void)in_sizes; (void)n_in; (void)out_size; (void)ws_size;
    const float* Q    = (const float*)d_in[0];
    const float* K    = (const float*)d_in[1];
    const float* V    = (const float*)d_in[2];
    const int*   mask = (const int*)d_in[3];

    float* out0   = (float*)d_out;          // (B, D) = 4096 floats
    float* p      = out0 + NB * ND;         // p_attn (B, SQ, SKV)
    float* colsum = (float*)d_ws;           // (B, SKV) floats

    hipMemsetAsync(colsum, 0, NB * NSKV * sizeof(float), stream);
    hipMemsetAsync(out0, 0, NB * ND * sizeof(float), stream);

    attn_e_kernel<<<NB * 16, 256, 0, stream>>>(Q, K, mask, p, colsum);
    attn_out_kernel<<<NB * 16, 256, 0, stream>>>(colsum, V, out0);
}